// Round 1
// baseline (212.696 us; speedup 1.0000x reference)
//
#include <hip/hip_runtime.h>
#include <hip/hip_bf16.h>

#define B_   2
#define T_   2048
#define D_   1024
#define H_   16
#define HD_  64
#define M_TOT (B_*T_)    // 4096
#define N_QKV (3*D_)     // 3072

typedef __attribute__((ext_vector_type(8))) short bf16x8;
typedef __attribute__((ext_vector_type(4))) float f32x4;

static __device__ __forceinline__ short f2bf(float f) {
    union { __hip_bfloat16 h; short s; } u;
    u.h = __float2bfloat16(f);
    return u.s;
}

// ---------------------------------------------------------------------------
// x fp32 -> bf16, straight copy (8 elems/thread)
__global__ __launch_bounds__(256) void convert_x(const float* __restrict__ x,
                                                 short* __restrict__ xb, int n8) {
    int i = blockIdx.x * blockDim.x + threadIdx.x;
    if (i >= n8) return;
    const float4* p = (const float4*)x + (size_t)i * 2;
    float4 a = p[0], b = p[1];
    bf16x8 o;
    o[0]=f2bf(a.x); o[1]=f2bf(a.y); o[2]=f2bf(a.z); o[3]=f2bf(a.w);
    o[4]=f2bf(b.x); o[5]=f2bf(b.y); o[6]=f2bf(b.z); o[7]=f2bf(b.w);
    *((bf16x8*)xb + i) = o;
}

// in [K][N] fp32  ->  out [N][K] bf16 (B^T layout for GEMM), 64x64 LDS tiles
__global__ __launch_bounds__(256) void transpose_convert(const float* __restrict__ in,
                                                         short* __restrict__ out,
                                                         int K, int N) {
    __shared__ short tile[64][65];
    int k0 = blockIdx.y * 64, n0 = blockIdx.x * 64;
    int t = threadIdx.x;
    #pragma unroll
    for (int i = 0; i < 16; ++i) {
        int idx = i * 256 + t;
        int r = idx >> 6, c = idx & 63;
        tile[r][c] = f2bf(in[(size_t)(k0 + r) * N + n0 + c]);
    }
    __syncthreads();
    #pragma unroll
    for (int i = 0; i < 16; ++i) {
        int idx = i * 256 + t;
        int r = idx >> 6, c = idx & 63;     // r: n-local, c: k-local
        out[(size_t)(n0 + r) * K + k0 + c] = tile[c][r];
    }
}

// ---------------------------------------------------------------------------
// C = A[M][K] * BT[N][K]^T + bias.  64x64 tile, BK=64, 4 waves (16 M-rows each).
// MODE 0: scatter into q[B,H,T,Hd], k[B,H,T,Hd], vT[B,H,Hd,T]  (bf16)
// MODE 1: write fp32 C to fo[M][N]
template<int MODE>
__global__ __launch_bounds__(256)
void gemm_bf16(const short* __restrict__ A, const short* __restrict__ BT,
               const float* __restrict__ bias, int M, int N, int K,
               short* __restrict__ qo, short* __restrict__ ko,
               short* __restrict__ vo, float* __restrict__ fo) {
    __shared__ char smem[16384];
    char* sA = smem;
    char* sB = smem + 8192;
    const int t = threadIdx.x, w = t >> 6, l = t & 63;
    const int m0 = blockIdx.y * 64, n0 = blockIdx.x * 64;

    f32x4 acc[4];
    #pragma unroll
    for (int nt = 0; nt < 4; ++nt) acc[nt] = (f32x4){0.f, 0.f, 0.f, 0.f};

    for (int k0 = 0; k0 < K; k0 += 64) {
        __syncthreads();
        #pragma unroll
        for (int i = 0; i < 2; ++i) {
            int idx = i * 256 + t;
            int row = idx >> 3, ch = idx & 7;
            int ad = (row * 128 + ch * 16) ^ ((row & 7) << 4);
            bf16x8 va = *(const bf16x8*)(A  + (size_t)(m0 + row) * K + k0 + ch * 8);
            *(bf16x8*)(sA + ad) = va;
            bf16x8 vb = *(const bf16x8*)(BT + (size_t)(n0 + row) * K + k0 + ch * 8);
            *(bf16x8*)(sB + ad) = vb;
        }
        __syncthreads();
        #pragma unroll
        for (int ks = 0; ks < 2; ++ks) {
            int arow = 16 * w + (l & 15);
            int aad = (arow * 128 + ks * 64 + (l >> 4) * 16) ^ ((arow & 7) << 4);
            bf16x8 af = *(const bf16x8*)(sA + aad);
            #pragma unroll
            for (int nt = 0; nt < 4; ++nt) {
                int brow = nt * 16 + (l & 15);
                int bad = (brow * 128 + ks * 64 + (l >> 4) * 16) ^ ((brow & 7) << 4);
                bf16x8 bf = *(const bf16x8*)(sB + bad);
                acc[nt] = __builtin_amdgcn_mfma_f32_16x16x32_bf16(af, bf, acc[nt], 0, 0, 0);
            }
        }
    }

    const int rbase = m0 + 16 * w + 4 * (l >> 4);
    #pragma unroll
    for (int nt = 0; nt < 4; ++nt) {
        int n = n0 + nt * 16 + (l & 15);
        float bv = bias[n];
        #pragma unroll
        for (int r = 0; r < 4; ++r) {
            int m = rbase + r;
            float c = acc[nt][r] + bv;
            if (MODE == 0) {
                int which = n >> 10, rest = n & 1023;
                int h = rest >> 6, d = rest & 63;
                int b = m >> 11, tq = m & 2047;
                size_t bh = (size_t)(b * H_ + h);
                if (which == 0)      qo[(bh * T_ + tq) * HD_ + d] = f2bf(c);
                else if (which == 1) ko[(bh * T_ + tq) * HD_ + d] = f2bf(c);
                else                 vo[(bh * HD_ + d) * T_ + tq] = f2bf(c);
            } else {
                fo[(size_t)m * N + n] = c;
            }
        }
    }
}

// ---------------------------------------------------------------------------
// Flash attention. q,k: [B*H, T, Hd] bf16;  vt: [B*H, Hd, T] bf16.
// Block = 64 q-rows (4 waves x 16), loop over 64-key tiles, online softmax.
__global__ __launch_bounds__(256)
void attn(const short* __restrict__ q, const short* __restrict__ k,
          const short* __restrict__ vt, short* __restrict__ ao) {
    __shared__ char smem[24576];
    char* sK = smem;            // [64 keys][64 d] bf16, swizzled
    char* sV = smem + 8192;     // [64 d][64 keys] bf16, swizzled
    char* sP = smem + 16384;    // per-wave [16 q][64 keys] bf16, swizzled

    const int t = threadIdx.x, w = t >> 6, l = t & 63;
    const int bh = blockIdx.y;
    const int q0 = blockIdx.x * 64 + 16 * w;

    const short* qptr = q + ((size_t)bh * T_ + q0) * HD_;
    const short* kbase = k + (size_t)bh * T_ * HD_;
    const short* vbase = vt + (size_t)bh * HD_ * T_;

    bf16x8 qa[2];
    qa[0] = *(const bf16x8*)(qptr + (l & 15) * HD_ + (l >> 4) * 8);
    qa[1] = *(const bf16x8*)(qptr + (l & 15) * HD_ + 32 + (l >> 4) * 8);

    f32x4 o[4];
    #pragma unroll
    for (int dt = 0; dt < 4; ++dt) o[dt] = (f32x4){0.f, 0.f, 0.f, 0.f};
    float mrow[4] = {-INFINITY, -INFINITY, -INFINITY, -INFINITY};
    float lrow[4] = {0.f, 0.f, 0.f, 0.f};

    for (int kb = 0; kb < T_; kb += 64) {
        __syncthreads();
        // stage K tile [64][64] and V^T tile [64][64] (both plain row-major copies)
        #pragma unroll
        for (int i = 0; i < 2; ++i) {
            int idx = i * 256 + t;
            int row = idx >> 3, ch = idx & 7;
            int ad = (row * 128 + ch * 16) ^ ((row & 7) << 4);
            bf16x8 vk = *(const bf16x8*)(kbase + (size_t)(kb + row) * HD_ + ch * 8);
            *(bf16x8*)(sK + ad) = vk;
            bf16x8 vv = *(const bf16x8*)(vbase + (size_t)row * T_ + kb + ch * 8);
            *(bf16x8*)(sV + ad) = vv;
        }
        __syncthreads();

        // S = Q K^T * 1/sqrt(Hd)
        f32x4 s[4];
        #pragma unroll
        for (int nt = 0; nt < 4; ++nt) s[nt] = (f32x4){0.f, 0.f, 0.f, 0.f};
        #pragma unroll
        for (int ks = 0; ks < 2; ++ks) {
            #pragma unroll
            for (int nt = 0; nt < 4; ++nt) {
                int brow = nt * 16 + (l & 15);
                int bad = (brow * 128 + ks * 64 + (l >> 4) * 16) ^ ((brow & 7) << 4);
                bf16x8 kf = *(const bf16x8*)(sK + bad);
                s[nt] = __builtin_amdgcn_mfma_f32_16x16x32_bf16(qa[ks], kf, s[nt], 0, 0, 0);
            }
        }
        #pragma unroll
        for (int nt = 0; nt < 4; ++nt) s[nt] *= 0.125f;

        // online softmax: rows handled per lane = 4*(l>>4)+r
        float tmax[4];
        #pragma unroll
        for (int r = 0; r < 4; ++r)
            tmax[r] = fmaxf(fmaxf(s[0][r], s[1][r]), fmaxf(s[2][r], s[3][r]));
        #pragma unroll
        for (int mask = 1; mask < 16; mask <<= 1) {
            #pragma unroll
            for (int r = 0; r < 4; ++r)
                tmax[r] = fmaxf(tmax[r], __shfl_xor(tmax[r], mask));
        }
        float mnew[4], fsc[4];
        #pragma unroll
        for (int r = 0; r < 4; ++r) {
            mnew[r] = fmaxf(mrow[r], tmax[r]);
            fsc[r]  = __expf(mrow[r] - mnew[r]);
            mrow[r] = mnew[r];
        }
        float rsum[4] = {0.f, 0.f, 0.f, 0.f};
        #pragma unroll
        for (int nt = 0; nt < 4; ++nt) {
            #pragma unroll
            for (int r = 0; r < 4; ++r) {
                float p = __expf(s[nt][r] - mnew[r]);
                rsum[r] += p;
                int prow = 4 * (l >> 4) + r;
                int pcol = nt * 16 + (l & 15);
                int ad = w * 2048 + ((prow * 128 + pcol * 2) ^ ((prow & 7) << 4));
                *(short*)(sP + ad) = f2bf(p);
            }
        }
        #pragma unroll
        for (int mask = 1; mask < 16; mask <<= 1) {
            #pragma unroll
            for (int r = 0; r < 4; ++r)
                rsum[r] += __shfl_xor(rsum[r], mask);
        }
        #pragma unroll
        for (int r = 0; r < 4; ++r) lrow[r] = lrow[r] * fsc[r] + rsum[r];
        #pragma unroll
        for (int dt = 0; dt < 4; ++dt) {
            #pragma unroll
            for (int r = 0; r < 4; ++r) o[dt][r] *= fsc[r];
        }
        __syncthreads();   // P visible (and everyone done with this tile's S reads)

        // O += P V : A-frag from sP (row = l&15), B-frag from sV (row = d-tile)
        #pragma unroll
        for (int ks = 0; ks < 2; ++ks) {
            int pad_ = w * 2048 + ((((l & 15) * 128) + ks * 64 + (l >> 4) * 16) ^ ((l & 7) << 4));
            bf16x8 pf = *(const bf16x8*)(sP + pad_);
            #pragma unroll
            for (int dt = 0; dt < 4; ++dt) {
                int vrow = dt * 16 + (l & 15);
                int vad = (vrow * 128 + ks * 64 + (l >> 4) * 16) ^ ((vrow & 7) << 4);
                bf16x8 vf = *(const bf16x8*)(sV + vad);
                o[dt] = __builtin_amdgcn_mfma_f32_16x16x32_bf16(pf, vf, o[dt], 0, 0, 0);
            }
        }
    }

    const int b = bh >> 4, h = bh & 15;
    #pragma unroll
    for (int dt = 0; dt < 4; ++dt) {
        #pragma unroll
        for (int r = 0; r < 4; ++r) {
            int tq = q0 + 4 * (l >> 4) + r;
            int d = dt * 16 + (l & 15);
            float val = o[dt][r] / lrow[r];
            ao[((size_t)(b * T_ + tq)) * D_ + h * HD_ + d] = f2bf(val);
        }
    }
}

// ---------------------------------------------------------------------------
extern "C" void kernel_launch(void* const* d_in, const int* in_sizes, int n_in,
                              void* d_out, int out_size, void* d_ws, size_t ws_size,
                              hipStream_t stream) {
    const float* x    = (const float*)d_in[0];
    const float* Wqkv = (const float*)d_in[1];
    const float* bqkv = (const float*)d_in[2];
    const float* Wout = (const float*)d_in[3];
    const float* bout = (const float*)d_in[4];
    float* out = (float*)d_out;

    char* ws = (char*)d_ws;
    short* xb  = (short*)(ws);                      // 8 MB  x bf16 [4096][1024]
    short* WqT = (short*)(ws + ((size_t)8  << 20)); // 6 MB  Wqkv^T bf16 [3072][1024]
    short* WoT = (short*)(ws + ((size_t)14 << 20)); // 2 MB  Wout^T bf16 [1024][1024]
    short* qb  = (short*)(ws + ((size_t)16 << 20)); // 8 MB  q [B*H][T][Hd]
    short* kb  = (short*)(ws + ((size_t)24 << 20)); // 8 MB  k [B*H][T][Hd]
    short* vtb = (short*)(ws + ((size_t)32 << 20)); // 8 MB  v^T [B*H][Hd][T]
    short* aob = (short*)(ws + ((size_t)40 << 20)); // 8 MB  attn out bf16 [4096][1024]

    convert_x<<<(M_TOT * D_ / 8 + 255) / 256, 256, 0, stream>>>(x, xb, M_TOT * D_ / 8);
    transpose_convert<<<dim3(N_QKV / 64, D_ / 64), 256, 0, stream>>>(Wqkv, WqT, D_, N_QKV);
    transpose_convert<<<dim3(D_ / 64, D_ / 64), 256, 0, stream>>>(Wout, WoT, D_, D_);

    gemm_bf16<0><<<dim3(N_QKV / 64, M_TOT / 64), 256, 0, stream>>>(
        xb, WqT, bqkv, M_TOT, N_QKV, D_, qb, kb, vtb, nullptr);

    attn<<<dim3(T_ / 64, B_ * H_), 256, 0, stream>>>(qb, kb, vtb, aob);

    gemm_bf16<1><<<dim3(D_ / 64, M_TOT / 64), 256, 0, stream>>>(
        aob, WoT, bout, M_TOT, D_, D_, nullptr, nullptr, nullptr, out);
}

// Round 3
// 158.968 us; speedup vs baseline: 1.3380x; 1.3380x over previous
//
#include <hip/hip_runtime.h>
#include <hip/hip_bf16.h>

#define B_   2
#define T_   2048
#define D_   1024
#define H_   16
#define HD_  64
#define M_TOT (B_*T_)    // 4096
#define N_QKV (3*D_)     // 3072

typedef __attribute__((ext_vector_type(8))) short bf16x8;
typedef __attribute__((ext_vector_type(4))) float f32x4;

static __device__ __forceinline__ short f2bf(float f) {
    union { __hip_bfloat16 h; short s; } u;
    u.h = __float2bfloat16(f);
    return u.s;
}
static __device__ __forceinline__ unsigned pack2(float a, float b) {
    return (unsigned)(unsigned short)f2bf(a) | ((unsigned)(unsigned short)f2bf(b) << 16);
}
// 2^x via v_exp_f32 (hardware exp is base-2)
static __device__ __forceinline__ float exp2_fast(float x) {
    return __builtin_amdgcn_exp2f(x);
}

// ---------------------------------------------------------------------------
// x fp32 -> bf16, straight copy (8 elems/thread)
__global__ __launch_bounds__(256) void convert_x(const float* __restrict__ x,
                                                 short* __restrict__ xb, int n8) {
    int i = blockIdx.x * blockDim.x + threadIdx.x;
    if (i >= n8) return;
    const float4* p = (const float4*)x + (size_t)i * 2;
    float4 a = p[0], b = p[1];
    bf16x8 o;
    o[0]=f2bf(a.x); o[1]=f2bf(a.y); o[2]=f2bf(a.z); o[3]=f2bf(a.w);
    o[4]=f2bf(b.x); o[5]=f2bf(b.y); o[6]=f2bf(b.z); o[7]=f2bf(b.w);
    *((bf16x8*)xb + i) = o;
}

// in [K][N] fp32  ->  out [N][K] bf16 (B^T layout for GEMM), 64x64 LDS tiles
__global__ __launch_bounds__(256) void transpose_convert(const float* __restrict__ in,
                                                         short* __restrict__ out,
                                                         int K, int N) {
    __shared__ short tile[64][65];
    int k0 = blockIdx.y * 64, n0 = blockIdx.x * 64;
    int t = threadIdx.x;
    #pragma unroll
    for (int i = 0; i < 16; ++i) {
        int idx = i * 256 + t;
        int r = idx >> 6, c = idx & 63;
        tile[r][c] = f2bf(in[(size_t)(k0 + r) * N + n0 + c]);
    }
    __syncthreads();
    #pragma unroll
    for (int i = 0; i < 16; ++i) {
        int idx = i * 256 + t;
        int r = idx >> 6, c = idx & 63;     // r: n-local, c: k-local
        out[(size_t)(n0 + r) * K + k0 + c] = tile[c][r];
    }
}

// ---------------------------------------------------------------------------
// C = A[M][K] * BT[N][K]^T + bias.  64x64 tile, BK=64, 4 waves (16 M-rows each).
// MODE 0: scatter into q[B,H,T,Hd] (pre-scaled by 1/sqrt(Hd)*log2e), k[B,H,T,Hd],
//         vT[B,H,Hd,T]  (bf16)
// MODE 1: write fp32 C to fo[M][N]
#define QSC 0.18033688f   // 0.125 * log2(e)
template<int MODE>
__global__ __launch_bounds__(256)
void gemm_bf16(const short* __restrict__ A, const short* __restrict__ BT,
               const float* __restrict__ bias, int M, int N, int K,
               short* __restrict__ qo, short* __restrict__ ko,
               short* __restrict__ vo, float* __restrict__ fo) {
    __shared__ char smem[16384];
    char* sA = smem;
    char* sB = smem + 8192;
    const int t = threadIdx.x, w = t >> 6, l = t & 63;
    const int m0 = blockIdx.y * 64, n0 = blockIdx.x * 64;

    f32x4 acc[4];
    #pragma unroll
    for (int nt = 0; nt < 4; ++nt) acc[nt] = (f32x4){0.f, 0.f, 0.f, 0.f};

    for (int k0 = 0; k0 < K; k0 += 64) {
        __syncthreads();
        #pragma unroll
        for (int i = 0; i < 2; ++i) {
            int idx = i * 256 + t;
            int row = idx >> 3, ch = idx & 7;
            int ad = (row * 128 + ch * 16) ^ ((row & 7) << 4);
            bf16x8 va = *(const bf16x8*)(A  + (size_t)(m0 + row) * K + k0 + ch * 8);
            *(bf16x8*)(sA + ad) = va;
            bf16x8 vb = *(const bf16x8*)(BT + (size_t)(n0 + row) * K + k0 + ch * 8);
            *(bf16x8*)(sB + ad) = vb;
        }
        __syncthreads();
        #pragma unroll
        for (int ks = 0; ks < 2; ++ks) {
            int arow = 16 * w + (l & 15);
            int aad = (arow * 128 + ks * 64 + (l >> 4) * 16) ^ ((arow & 7) << 4);
            bf16x8 af = *(const bf16x8*)(sA + aad);
            #pragma unroll
            for (int nt = 0; nt < 4; ++nt) {
                int brow = nt * 16 + (l & 15);
                int bad = (brow * 128 + ks * 64 + (l >> 4) * 16) ^ ((brow & 7) << 4);
                bf16x8 bf = *(const bf16x8*)(sB + bad);
                acc[nt] = __builtin_amdgcn_mfma_f32_16x16x32_bf16(af, bf, acc[nt], 0, 0, 0);
            }
        }
    }

    const int rbase = m0 + 16 * w + 4 * (l >> 4);
    #pragma unroll
    for (int nt = 0; nt < 4; ++nt) {
        int n = n0 + nt * 16 + (l & 15);
        float bv = bias[n];
        #pragma unroll
        for (int r = 0; r < 4; ++r) {
            int m = rbase + r;
            float c = acc[nt][r] + bv;
            if (MODE == 0) {
                int which = n >> 10, rest = n & 1023;
                int h = rest >> 6, d = rest & 63;
                int b = m >> 11, tq = m & 2047;
                size_t bh = (size_t)(b * H_ + h);
                if (which == 0)      qo[(bh * T_ + tq) * HD_ + d] = f2bf(c * QSC);
                else if (which == 1) ko[(bh * T_ + tq) * HD_ + d] = f2bf(c);
                else                 vo[(bh * HD_ + d) * T_ + tq] = f2bf(c);
            } else {
                fo[(size_t)m * N + n] = c;
            }
        }
    }
}

// ---------------------------------------------------------------------------
// Flash attention, swapped-QK^T form. q,k: [B*H, T, Hd] bf16 (q pre-scaled by
// 1/sqrt(Hd)*log2e);  vt: [B*H, Hd, T] bf16.
// Block = 64 q-rows (4 waves x 16). Per k-tile:
//   S^T = mfma(K_frag, Q_frag)  -> lane holds 16 k-values of ONE q-row
//   in-register softmax (in-lane reduce + 2 shfl across hi-groups)
//   P packed to wave-local LDS (4x ds_write_b64), no barrier (intra-wave)
//   O^T += mfma(V^T_frag, P^T_frag)
__global__ __launch_bounds__(256)
void attn(const short* __restrict__ q, const short* __restrict__ k,
          const short* __restrict__ vt, short* __restrict__ ao) {
    __shared__ char smem[24576];
    char* sK = smem;            // [64 keys][64 d] bf16, swizzled
    char* sV = smem + 8192;     // [64 d][64 keys] bf16, swizzled
    char* sP = smem + 16384;    // per-wave [16 q][64 k] bf16, swizzled

    const int t = threadIdx.x, w = t >> 6, l = t & 63;
    const int qi = l & 15, hi = l >> 4;
    const int swz = (qi & 7) << 4;
    const int bh = blockIdx.y;
    const int q0 = blockIdx.x * 64 + 16 * w;

    const short* qptr = q + ((size_t)bh * T_ + q0) * HD_;
    const short* kbase = k + (size_t)bh * T_ * HD_;
    const short* vbase = vt + (size_t)bh * HD_ * T_;
    char* sPw = sP + w * 2048;

    bf16x8 qa[2];
    qa[0] = *(const bf16x8*)(qptr + qi * HD_ + hi * 8);
    qa[1] = *(const bf16x8*)(qptr + qi * HD_ + 32 + hi * 8);

    f32x4 o[4];
    #pragma unroll
    for (int dt = 0; dt < 4; ++dt) o[dt] = (f32x4){0.f, 0.f, 0.f, 0.f};
    float m = -1e30f, lsum = 0.f;

    for (int kb = 0; kb < T_; kb += 64) {
        __syncthreads();
        // stage K tile [64][64] and V^T tile [64][64] (plain row-major copies)
        #pragma unroll
        for (int i = 0; i < 2; ++i) {
            int idx = i * 256 + t;
            int row = idx >> 3, ch = idx & 7;
            int ad = (row * 128 + ch * 16) ^ ((row & 7) << 4);
            bf16x8 vk = *(const bf16x8*)(kbase + (size_t)(kb + row) * HD_ + ch * 8);
            *(bf16x8*)(sK + ad) = vk;
            bf16x8 vv = *(const bf16x8*)(vbase + (size_t)row * T_ + kb + ch * 8);
            *(bf16x8*)(sV + ad) = vv;
        }
        __syncthreads();

        // S^T tile: s[nt][r] = S[k = nt*16 + 4*hi + r][q = qi]  (log2-domain)
        f32x4 s[4];
        #pragma unroll
        for (int nt = 0; nt < 4; ++nt) s[nt] = (f32x4){0.f, 0.f, 0.f, 0.f};
        #pragma unroll
        for (int ks = 0; ks < 2; ++ks) {
            #pragma unroll
            for (int nt = 0; nt < 4; ++nt) {
                int kad = ((nt * 16 + qi) * 128 + ks * 64 + hi * 16) ^ swz;
                bf16x8 kf = *(const bf16x8*)(sK + kad);
                s[nt] = __builtin_amdgcn_mfma_f32_16x16x32_bf16(kf, qa[ks], s[nt], 0, 0, 0);
            }
        }

        // row max: 16 in-lane values, then across the 4 hi-groups
        float t0 = fmaxf(fmaxf(s[0][0], s[0][1]), fmaxf(s[0][2], s[0][3]));
        float t1 = fmaxf(fmaxf(s[1][0], s[1][1]), fmaxf(s[1][2], s[1][3]));
        float t2 = fmaxf(fmaxf(s[2][0], s[2][1]), fmaxf(s[2][2], s[2][3]));
        float t3 = fmaxf(fmaxf(s[3][0], s[3][1]), fmaxf(s[3][2], s[3][3]));
        float tm = fmaxf(fmaxf(t0, t1), fmaxf(t2, t3));
        tm = fmaxf(tm, __shfl_xor(tm, 16));
        tm = fmaxf(tm, __shfl_xor(tm, 32));

        // defer-max (T13): skip O-rescale when max growth <= 8 (log2 domain)
        if (!__all(tm <= m + 8.f)) {
            float mnew = fmaxf(m, tm);
            float fsc = exp2_fast(m - mnew);
            lsum *= fsc;
            #pragma unroll
            for (int dt = 0; dt < 4; ++dt) {
                #pragma unroll
                for (int r = 0; r < 4; ++r) o[dt][r] *= fsc;
            }
            m = mnew;
        }

        // P = exp2(S - m), accumulate row-sum, pack to LDS
        float psum = 0.f;
        #pragma unroll
        for (int nt = 0; nt < 4; ++nt) {
            #pragma unroll
            for (int r = 0; r < 4; ++r) {
                s[nt][r] = exp2_fast(s[nt][r] - m);
                psum += s[nt][r];
            }
            uint2 pk;
            pk.x = pack2(s[nt][0], s[nt][1]);
            pk.y = pack2(s[nt][2], s[nt][3]);
            int ab = (qi * 128 + nt * 32 + hi * 8) ^ swz;
            *(uint2*)(sPw + ab) = pk;
        }
        psum += __shfl_xor(psum, 16);
        psum += __shfl_xor(psum, 32);
        lsum += psum;

        // wave-local P: no __syncthreads needed, just drain the DS queue
        asm volatile("s_waitcnt lgkmcnt(0)" ::: "memory");

        // O^T += V^T P^T
        #pragma unroll
        for (int ks = 0; ks < 2; ++ks) {
            int pad_ = (qi * 128 + ks * 64 + hi * 16) ^ swz;
            bf16x8 pf = *(const bf16x8*)(sPw + pad_);
            #pragma unroll
            for (int dt = 0; dt < 4; ++dt) {
                int vad = ((dt * 16 + qi) * 128 + ks * 64 + hi * 16) ^ swz;
                bf16x8 vf = *(const bf16x8*)(sV + vad);
                o[dt] = __builtin_amdgcn_mfma_f32_16x16x32_bf16(vf, pf, o[dt], 0, 0, 0);
            }
        }
    }

    const float inv = 1.f / lsum;
    const int b = bh >> 4, h = bh & 15;
    const int tq = q0 + qi;
    #pragma unroll
    for (int dt = 0; dt < 4; ++dt) {
        #pragma unroll
        for (int r = 0; r < 4; ++r) {
            int d = dt * 16 + 4 * hi + r;
            ao[((size_t)(b * T_ + tq)) * D_ + h * HD_ + d] = f2bf(o[dt][r] * inv);
        }
    }
}

// ---------------------------------------------------------------------------
extern "C" void kernel_launch(void* const* d_in, const int* in_sizes, int n_in,
                              void* d_out, int out_size, void* d_ws, size_t ws_size,
                              hipStream_t stream) {
    const float* x    = (const float*)d_in[0];
    const float* Wqkv = (const float*)d_in[1];
    const float* bqkv = (const float*)d_in[2];
    const float* Wout = (const float*)d_in[3];
    const float* bout = (const float*)d_in[4];
    float* out = (float*)d_out;

    char* ws = (char*)d_ws;
    short* xb  = (short*)(ws);                      // 8 MB  x bf16 [4096][1024]
    short* WqT = (short*)(ws + ((size_t)8  << 20)); // 6 MB  Wqkv^T bf16 [3072][1024]
    short* WoT = (short*)(ws + ((size_t)14 << 20)); // 2 MB  Wout^T bf16 [1024][1024]
    short* qb  = (short*)(ws + ((size_t)16 << 20)); // 8 MB  q [B*H][T][Hd]
    short* kb  = (short*)(ws + ((size_t)24 << 20)); // 8 MB  k [B*H][T][Hd]
    short* vtb = (short*)(ws + ((size_t)32 << 20)); // 8 MB  v^T [B*H][Hd][T]
    short* aob = (short*)(ws + ((size_t)40 << 20)); // 8 MB  attn out bf16 [4096][1024]

    convert_x<<<(M_TOT * D_ / 8 + 255) / 256, 256, 0, stream>>>(x, xb, M_TOT * D_ / 8);
    transpose_convert<<<dim3(N_QKV / 64, D_ / 64), 256, 0, stream>>>(Wqkv, WqT, D_, N_QKV);
    transpose_convert<<<dim3(D_ / 64, D_ / 64), 256, 0, stream>>>(Wout, WoT, D_, D_);

    gemm_bf16<0><<<dim3(N_QKV / 64, M_TOT / 64), 256, 0, stream>>>(
        xb, WqT, bqkv, M_TOT, N_QKV, D_, qb, kb, vtb, nullptr);

    attn<<<dim3(T_ / 64, B_ * H_), 256, 0, stream>>>(qb, kb, vtb, aob);

    gemm_bf16<1><<<dim3(D_ / 64, M_TOT / 64), 256, 0, stream>>>(
        aob, WoT, bout, M_TOT, D_, D_, nullptr, nullptr, nullptr, out);
}